// Round 8
// baseline (131.054 us; speedup 1.0000x reference)
//
#include <hip/hip_runtime.h>
#include <math.h>

#define L_SEQ 16384
#define H_DIM 1024
#define P_DIM 512
#define N2P   1024
#define KDIM  1024
#define NKT   16     // KDIM / 64 K-tiles
#define CHUNK 64
#define NCHUNK 256   // L_SEQ / CHUNK

typedef __attribute__((ext_vector_type(8))) short short8;
typedef __attribute__((ext_vector_type(4))) float f32x4;

__device__ __forceinline__ unsigned short f2bf(float f){
    unsigned int u = __float_as_uint(f);
    u = (u + 0x7FFFu + ((u >> 16) & 1u)) >> 16;
    return (unsigned short)u;
}
__device__ __forceinline__ float bf2f(unsigned int lo16){
    return __uint_as_float(lo16 << 16);
}

// ---------------- prep ----------------
__global__ void k_prep_lambda(const float* __restrict__ lre, const float* __restrict__ lim,
                              const float* __restrict__ lstep,
                              float* __restrict__ lam, float* __restrict__ coef,
                              float* __restrict__ lpow)
{
    int p = threadIdx.x;
    double step = exp((double)lstep[p]);
    double dr = (double)lre[p], di = (double)lim[p];
    double ar = dr*step, ai = di*step;
    double er = exp(ar);
    double lbr = er*cos(ai), lbi = er*sin(ai);
    lam[2*p] = (float)lbr; lam[2*p+1] = (float)lbi;
    double nr = lbr - 1.0, ni = lbi;
    double d2 = dr*dr + di*di;
    coef[2*p]   = (float)((nr*dr + ni*di)/d2);
    coef[2*p+1] = (float)((ni*dr - nr*di)/d2);
    double xr = lbr, xi = lbi;
    #pragma unroll
    for (int s=0;s<6;s++){ double t = xr*xr - xi*xi; xi = 2.0*xr*xi; xr = t; } // ^64
    lpow[2*p] = (float)xr; lpow[2*p+1] = (float)xi;
}

__global__ __launch_bounds__(256)
void k_prep_BB(const float* __restrict__ B, const float* __restrict__ coef,
               unsigned short* __restrict__ BB)
{
    int i = blockIdx.x*256 + threadIdx.x;   // i = p*H + h
    int p = i >> 10, h = i & 1023;
    float br = B[2*i], bi = B[2*i+1];
    float cr = coef[2*p], ci = coef[2*p+1];
    BB[(size_t)(2*p)*H_DIM + h]   = f2bf(cr*br - ci*bi);
    BB[(size_t)(2*p+1)*H_DIM + h] = f2bf(cr*bi + ci*br);
}

__global__ __launch_bounds__(256)
void k_prep_CC(const float* __restrict__ C, unsigned short* __restrict__ CC)
{
    int i = blockIdx.x*256 + threadIdx.x;   // i = h*P + p
    int h = i >> 9, p = i & 511;
    float cr = C[2*i], ci = C[2*i+1];
    CC[(size_t)h*N2P + 2*p]     = f2bf(2.f*cr);
    CC[(size_t)h*N2P + 2*p + 1] = f2bf(-2.f*ci);
}

__global__ __launch_bounds__(256)
void k_cast(const float4* __restrict__ u, unsigned short* __restrict__ o)
{
    int i = blockIdx.x*256 + threadIdx.x;
    float4 a = u[2*i], b = u[2*i+1];
    union { short8 v; unsigned short s[8]; } r;
    r.s[0]=f2bf(a.x); r.s[1]=f2bf(a.y); r.s[2]=f2bf(a.z); r.s[3]=f2bf(a.w);
    r.s[4]=f2bf(b.x); r.s[5]=f2bf(b.y); r.s[6]=f2bf(b.z); r.s[7]=f2bf(b.w);
    *reinterpret_cast<short8*>(o + (size_t)i*8) = r.v;
}

// ---------------- GEMM: 256x256, BK=64, 2-parity dbuf, compiler-scheduled body ----
// C[M][1024] = A[M][1024]bf16 @ Bm[1024][1024]bf16^T
// Per KT: stage A(kt+1),B(kt+1) into OTHER parity (no mid-KT conflict) ->
//   plain-deref ds_reads + MFMA in natural loops (compiler interleaves read-issue
//   under MFMA clusters; no volatile-asm fences) -> vmcnt(0) [free: issued a full
//   KT earlier] -> raw s_barrier (no __syncthreads drain).
// Swizzle (both sides, 0 conflicts measured): phys 16B-chunk = logical ^ (row&7).
template<int EPI>
__global__ __launch_bounds__(512, 2)
void gemm256(const unsigned short* __restrict__ A, const unsigned short* __restrict__ Bm,
             float* __restrict__ Cf, unsigned short* __restrict__ Cb,
             const float* __restrict__ Dv, const unsigned short* __restrict__ U16)
{
    __shared__ char lds[131072];
    const int tid  = threadIdx.x;
    const int lane = tid & 63;
    const int wid  = tid >> 6;
    const int wm = wid >> 2, wn = wid & 3;          // 2(M) x 4(N) waves
    const int wg = ((int)blockIdx.x & 7) * 32 + ((int)blockIdx.x >> 3);  // XCD swizzle
    const int tm = wg >> 2, tn = wg & 3;
    const int lr = lane & 15;

    // staging: thread covers half-tile row tid>>3 (+64 on 2nd load), 16B chunk tid&7.
    // gload dst linear; source col pre-swizzled: logical chunk = (tid&7)^(row&7).
    const int scol = ((tid & 7) ^ ((tid >> 3) & 7)) << 3;   // ushort units
    const int srow = tid >> 3;                               // 0..63
    // reads: row = 16*frag + lr; byte = row*128 + ((g|4ks)^(lr&7))*16, g=lane>>4
    const int kc0 = (((lane >> 4)      ^ (lr & 7)) << 4);
    const int kc1 = ((((lane >> 4) | 4) ^ (lr & 7)) << 4);
    const int aSub = wm*16384 + lr*128;                      // + m*2048
    const int bSub = 32768 + (wn >> 1)*16384 + (wn & 1)*8192 + lr*128;  // + n*2048

#define GLOAD(SRC, DST) __builtin_amdgcn_global_load_lds( \
        (const __attribute__((address_space(1))) void*)(SRC), \
        (__attribute__((address_space(3))) void*)(DST), 16, 0, 0)
#define STAGE_A(kt_, h_) do{ \
    char* d_ = lds + (((kt_)&1)<<16) + (h_)*16384 + tid*16; \
    const unsigned short* s_ = A + (size_t)(tm*256 + (h_)*128 + srow)*KDIM + (size_t)(kt_)*64 + scol; \
    GLOAD(s_, d_); GLOAD(s_ + (size_t)64*KDIM, d_ + 8192); }while(0)
#define STAGE_B(kt_, h_) do{ \
    char* d_ = lds + (((kt_)&1)<<16) + 32768 + (h_)*16384 + tid*16; \
    const unsigned short* s_ = Bm + (size_t)(tn*256 + (h_)*128 + srow)*KDIM + (size_t)(kt_)*64 + scol; \
    GLOAD(s_, d_); GLOAD(s_ + (size_t)64*KDIM, d_ + 8192); }while(0)
#define RD(OFF) (*(const short8*)(lds + (OFF)))
#define MFMA(a,b,c) __builtin_amdgcn_mfma_f32_16x16x32_bf16(a,b,c,0,0,0)
#define VMC0  asm volatile("s_waitcnt vmcnt(0)" ::: "memory")
#define ABAR  asm volatile("s_barrier" ::: "memory")

    f32x4 acc[8][4];
    #pragma unroll
    for (int m=0;m<8;m++)
        #pragma unroll
        for (int n=0;n<4;n++) acc[m][n] = (f32x4){0.f,0.f,0.f,0.f};

    // prologue: stage KT0 into parity 0; own-writes drained, then block barrier
    STAGE_A(0,0); STAGE_A(0,1); STAGE_B(0,0); STAGE_B(0,1);
    VMC0; ABAR;

    #pragma unroll 2
    for (int kt = 0; kt < NKT; ++kt) {
        const int sb = (kt & 1) << 16;
        const int tN = (kt+1 < NKT) ? kt+1 : NKT-1;   // tail dummy (other parity, never read)
        // issue next-KT stages first (writes to other parity; reads below untouched)
        STAGE_A(tN, 0); STAGE_A(tN, 1); STAGE_B(tN, 0); STAGE_B(tN, 1);

        // compute KT kt from buf[kt&1] — plain derefs, compiler-scheduled
        #pragma unroll
        for (int ks=0; ks<2; ++ks){
            const int kc = ks ? kc1 : kc0;
            short8 bfr[4];
            #pragma unroll
            for (int n=0;n<4;n++) bfr[n] = RD(sb + bSub + n*2048 + kc);
            #pragma unroll
            for (int mh=0; mh<2; ++mh){
                short8 afr[4];
                #pragma unroll
                for (int m=0;m<4;m++) afr[m] = RD(sb + aSub + (mh*4+m)*2048 + kc);
                #pragma unroll
                for (int m=0;m<4;m++)
                    #pragma unroll
                    for (int n=0;n<4;n++)
                        acc[mh*4+m][n] = MFMA(afr[m], bfr[n], acc[mh*4+m][n]);
            }
        }
        VMC0;   // own stage-writes done (issued ~a full KT of work ago)
        ABAR;   // all waves' reads of buf[kt&1] done; next KT may stage into it
    }

    const int orow0 = tm*256 + wm*128 + (lane>>4)*4;
    const int ocol0 = tn*256 + wn*64 + lr;
    #pragma unroll
    for (int m=0;m<8;m++){
        #pragma unroll
        for (int n=0;n<4;n++){
            int row = orow0 + m*16, col = ocol0 + n*16;
            #pragma unroll
            for (int j=0;j<4;j++){
                size_t idx = (size_t)(row + j)*N2P + col;
                if (EPI) Cf[idx] = acc[m][n][j] + Dv[col]*bf2f(U16[idx]);
                else     Cb[idx] = f2bf(acc[m][n][j]);
            }
        }
    }
#undef GLOAD
#undef STAGE_A
#undef STAGE_B
#undef RD
#undef MFMA
#undef VMC0
#undef ABAR
}

// ---------------- scan phase 1: per-(chunk, p) aggregate (Bu in bf16 pairs) -------
__global__ __launch_bounds__(512)
void k_agg(const unsigned int* __restrict__ Bu, const float* __restrict__ lam,
           float* __restrict__ agg)
{
    int p = threadIdx.x, c = blockIdx.x;
    float lrr = lam[2*p], lii = lam[2*p+1];
    float xr = 0.f, xi = 0.f;
    const unsigned int* b2 = Bu + (size_t)c*CHUNK*512 + p;
    #pragma unroll 4
    for (int t=0;t<CHUNK;t++){
        unsigned int b = b2[(size_t)t*512];
        float br = __uint_as_float(b << 16);
        float bi = __uint_as_float(b & 0xffff0000u);
        float tr = lrr*xr - lii*xi + br;
        xi = lrr*xi + lii*xr + bi;
        xr = tr;
    }
    agg[((size_t)c*P_DIM + p)*2]     = xr;
    agg[((size_t)c*P_DIM + p)*2 + 1] = xi;
}

// ---------------- scan phase 2: Kogge-Stone over chunks ---------------------
__global__ __launch_bounds__(256)
void k_scan(const float* __restrict__ agg, const float* __restrict__ lpow,
            float* __restrict__ xinit)
{
    __shared__ float sr[NCHUNK], si[NCHUNK];
    int c = threadIdx.x, p = blockIdx.x;
    float xr = agg[((size_t)c*P_DIM + p)*2];
    float xi = agg[((size_t)c*P_DIM + p)*2 + 1];
    sr[c] = xr; si[c] = xi;
    float wr = lpow[2*p], wi = lpow[2*p+1];
    for (int s=1; s<NCHUNK; s<<=1){
        __syncthreads();
        float ur = 0.f, ui = 0.f;
        if (c >= s){ ur = sr[c-s]; ui = si[c-s]; }
        __syncthreads();
        xr += wr*ur - wi*ui;
        xi += wr*ui + wi*ur;
        sr[c] = xr; si[c] = xi;
        float t = wr*wr - wi*wi; wi = 2.f*wr*wi; wr = t;
    }
    __syncthreads();
    float er = 0.f, ei = 0.f;
    if (c > 0){ er = sr[c-1]; ei = si[c-1]; }
    xinit[((size_t)c*P_DIM + p)*2]     = er;
    xinit[((size_t)c*P_DIM + p)*2 + 1] = ei;
}

// ---------------- scan phase 3: apply + emit bf16 pairs ----------------------
__global__ __launch_bounds__(512)
void k_apply(const unsigned int* __restrict__ Bu, const float* __restrict__ lam,
             const float* __restrict__ xinit, unsigned int* __restrict__ xs)
{
    int p = threadIdx.x, c = blockIdx.x;
    float lrr = lam[2*p], lii = lam[2*p+1];
    float xr = xinit[((size_t)c*P_DIM + p)*2];
    float xi = xinit[((size_t)c*P_DIM + p)*2 + 1];
    const unsigned int* b2 = Bu + (size_t)c*CHUNK*512 + p;
    unsigned int* o = xs + (size_t)c*CHUNK*512 + p;
    #pragma unroll 4
    for (int t=0;t<CHUNK;t++){
        unsigned int b = b2[(size_t)t*512];
        float br = __uint_as_float(b << 16);
        float bi = __uint_as_float(b & 0xffff0000u);
        float tr = lrr*xr - lii*xi + br;
        xi = lrr*xi + lii*xr + bi;
        xr = tr;
        o[(size_t)t*512] = (unsigned int)f2bf(xr) | ((unsigned int)f2bf(xi) << 16);
    }
}

extern "C" void kernel_launch(void* const* d_in, const int* in_sizes, int n_in,
                              void* d_out, int out_size, void* d_ws, size_t ws_size,
                              hipStream_t stream)
{
    const float* u   = (const float*)d_in[0];
    const float* lre = (const float*)d_in[1];
    const float* lim = (const float*)d_in[2];
    const float* B   = (const float*)d_in[3];
    const float* C   = (const float*)d_in[4];
    const float* D   = (const float*)d_in[5];
    const float* ls  = (const float*)d_in[6];
    float* out = (float*)d_out;

    char* w = (char*)d_ws;
    unsigned short* u16  = (unsigned short*)(w + 0);          // 32 MiB
    unsigned short* xs16 = (unsigned short*)(w + 33554432);   // 32 MiB
    unsigned short* Bu16 = (unsigned short*)(w + 67108864);   // 32 MiB
    unsigned short* BB   = (unsigned short*)(w + 100663296);  // 2 MiB
    unsigned short* CC   = (unsigned short*)(w + 102760448);  // 2 MiB
    float* lam   = (float*)(w + 104857600);
    float* coef  = (float*)(w + 104861696);
    float* lpow  = (float*)(w + 104865792);
    float* agg   = (float*)(w + 104869888);                   // 1 MiB
    float* xinit = (float*)(w + 105918464);                   // 1 MiB

    k_prep_lambda<<<1, P_DIM, 0, stream>>>(lre, lim, ls, lam, coef, lpow);
    k_prep_BB<<<(P_DIM*H_DIM)/256, 256, 0, stream>>>(B, coef, BB);
    k_prep_CC<<<(H_DIM*P_DIM)/256, 256, 0, stream>>>(C, CC);
    k_cast<<<(L_SEQ*H_DIM)/(256*8), 256, 0, stream>>>((const float4*)u, u16);

    gemm256<0><<<256, 512, 0, stream>>>(u16, BB, nullptr, Bu16, nullptr, nullptr);

    k_agg<<<NCHUNK, P_DIM, 0, stream>>>((const unsigned int*)Bu16, lam, agg);
    k_scan<<<P_DIM, NCHUNK, 0, stream>>>(agg, lpow, xinit);
    k_apply<<<NCHUNK, P_DIM, 0, stream>>>((const unsigned int*)Bu16, lam, xinit,
                                          (unsigned int*)xs16);

    gemm256<1><<<256, 512, 0, stream>>>(xs16, CC, out, nullptr, D, u16);
}